// Round 5
// baseline (80.265 us; speedup 1.0000x reference)
//
#include <hip/hip_runtime.h>

#define HH 256
#define WW 256
#define TT 32
#define PLANE (HH * WW)
#define CHUNK 8
#define NCH 4

struct alignas(16) F4 { float x, y, z, w; };
__device__ inline F4 operator+(F4 a, F4 b) { return {a.x+b.x, a.y+b.y, a.z+b.z, a.w+b.w}; }
__device__ inline F4 operator-(F4 a, F4 b) { return {a.x-b.x, a.y-b.y, a.z-b.z, a.w-b.w}; }
__device__ inline F4 operator*(F4 a, F4 b) { return {a.x*b.x, a.y*b.y, a.z*b.z, a.w*b.w}; }
__device__ inline F4 operator*(F4 a, float s) { return {a.x*s, a.y*s, a.z*s, a.w*s}; }
__device__ inline F4 operator*(float s, F4 a) { return {a.x*s, a.y*s, a.z*s, a.w*s}; }

__global__ __launch_bounds__(256) void pil_main(const float* __restrict__ p,
                                                const float* __restrict__ Kf,
                                                double* __restrict__ ws) {
  __shared__ double redN[4];
  __shared__ int redD[4];

  const int rg = blockIdx.x;      // row group 0..63 (4 rows per block)
  const int b = blockIdx.y;       // 0..15
  const int c = blockIdx.z;       // t-chunk 0..3
  const int t0 = c * CHUNK;
  const bool hasPre = (c != 0);
  const bool hasPost = (c != NCH - 1);

  const int tid = threadIdx.x;
  const int wid = tid >> 6;       // wave index = row within group
  const int lane = tid & 63;
  const int i = (rg << 2) + wid;  // global row (wave-uniform)
  const int j0 = lane << 2;       // first of 4 cols

  const float i2hx = 0.02f;       // 1/(2*25)
  const float i2hy = 0.01f;       // 1/(2*50)
  const float Sc = 2e-4f;

  // rolling per-point state (4 cols/thread)
  float cm2[4] = {0, 0, 0, 0}, cm1[4] = {0, 0, 0, 0};
  float dkA[4] = {0, 0, 0, 0}, dkB[4] = {0, 0, 0, 0};
  unsigned mAb = 0, mBb = 0;
  double accN = 0.0;
  int accD = 0;

  const size_t bbase = (size_t)b * TT * PLANE;

  // clamped row windows (wave-uniform): p rows pa..pa+4, K rows ka..ka+2
  int pa = i - 2; pa = pa < 0 ? 0 : pa; pa = pa > HH - 5 ? HH - 5 : pa;
  int ka = i - 1; ka = ka < 0 ? 0 : ka; ka = ka > HH - 3 ? HH - 3 : ka;
  // rowcase: 0 interior, 1: i==0, 2: i==1, 3: i==254, 4: i==255
  const int rowcase = (i >= 2 && i <= HH - 3) ? 0
                      : (i == 0 ? 1 : (i == 1 ? 2 : (i == HH - 2 ? 3 : 4)));

  // base pointers: middle row of each window, plane t0; neighbors via imm offsets
  const float* pb = p + bbase + (size_t)t0 * PLANE + (size_t)(pa + 2) * WW + j0;
  const float* kb = Kf + bbase + (size_t)t0 * PLANE + (size_t)(ka + 1) * WW + j0;
  const float* pcrow = p + bbase + (size_t)i * WW + j0;  // plane-0 center-row base

  F4 R[2][5], Kv[2][3];
  F4 chPre, chPost;

#define ISSUE8(B) do { \
    R[B][0] = *reinterpret_cast<const F4*>(pb - 2 * WW); \
    R[B][1] = *reinterpret_cast<const F4*>(pb - WW); \
    R[B][2] = *reinterpret_cast<const F4*>(pb); \
    R[B][3] = *reinterpret_cast<const F4*>(pb + WW); \
    R[B][4] = *reinterpret_cast<const F4*>(pb + 2 * WW); \
    Kv[B][0] = *reinterpret_cast<const F4*>(kb - WW); \
    Kv[B][1] = *reinterpret_cast<const F4*>(kb); \
    Kv[B][2] = *reinterpret_cast<const F4*>(kb + WW); \
  } while (0)

  // ---- prologue: pre-halo center row (c>0) + plane t0 into buffer 0 ----
  if (hasPre)
    chPre = *reinterpret_cast<const F4*>(pcrow + (size_t)(t0 - 1) * PLANE);
  ISSUE8(0);
  if (hasPre) {
    cm1[0] = chPre.x; cm1[1] = chPre.y; cm1[2] = chPre.z; cm1[3] = chPre.w;
  }

#pragma unroll
  for (int s = 0; s < CHUNK; ++s) {
    const int cur = s & 1;
    const int nxt = cur ^ 1;
    pb += PLANE; kb += PLANE;          // now at plane t0+s+1
    if (s < CHUNK - 1) {
      ISSUE8(nxt);                      // prefetch next plane
    } else if (hasPost) {
      chPost = *reinterpret_cast<const F4*>(pcrow + (size_t)(t0 + CHUNK) * PLANE);
    }

    const F4 r0v = R[cur][0], r1v = R[cur][1], r2v = R[cur][2],
             r3v = R[cur][3], r4v = R[cur][4];
    const F4 kAv = Kv[cur][0], kBv = Kv[cur][1], kCv = Kv[cur][2];

    // ---- x-direction terms (wave-uniform rowcase branch) ----
    F4 pdx4, t14, pdxx4, kdx4, kcen, pcen;
    if (rowcase == 0) {
      F4 gm = (r2v - r0v) * i2hx;
      F4 gp = (r4v - r2v) * i2hx;
      pdx4 = (r3v - r1v) * i2hx;
      t14 = (kCv * gp - kAv * gm) * i2hx;
      pdxx4 = (gp - gm) * i2hx;
      kdx4 = (kCv - kAv) * i2hx;
      kcen = kBv; pcen = r2v;
    } else if (rowcase == 1) {  // i==0 (pa=0, ka=0)
      F4 g0 = (4.0f * r1v - 3.0f * r0v - r2v) * i2hx;
      F4 g1 = (r2v - r0v) * i2hx;
      F4 g2 = (r3v - r1v) * i2hx;
      pdx4 = g0;
      t14 = (4.0f * (kBv * g1) - 3.0f * (kAv * g0) - kCv * g2) * i2hx;
      pdxx4 = (4.0f * g1 - 3.0f * g0 - g2) * i2hx;
      kdx4 = (4.0f * kBv - 3.0f * kAv - kCv) * i2hx;
      kcen = kAv; pcen = r0v;
    } else if (rowcase == 2) {  // i==1 (pa=0, ka=0)
      F4 gm = (4.0f * r1v - 3.0f * r0v - r2v) * i2hx;  // g(0) edge
      F4 gp = (r3v - r1v) * i2hx;                       // g(2)
      pdx4 = (r2v - r0v) * i2hx;
      t14 = (kCv * gp - kAv * gm) * i2hx;
      pdxx4 = (gp - gm) * i2hx;
      kdx4 = (kCv - kAv) * i2hx;
      kcen = kBv; pcen = r1v;
    } else if (rowcase == 3) {  // i==254 (pa=251, ka=253)
      F4 gm = (r3v - r1v) * i2hx;                        // g(253)
      F4 gp = (3.0f * r4v - 4.0f * r3v + r2v) * i2hx;    // g(255) edge
      pdx4 = (r4v - r2v) * i2hx;
      t14 = (kCv * gp - kAv * gm) * i2hx;
      pdxx4 = (gp - gm) * i2hx;
      kdx4 = (kCv - kAv) * i2hx;
      kcen = kBv; pcen = r3v;
    } else {  // i==255 (pa=251, ka=253)
      F4 gm2 = (r3v - r1v) * i2hx;                       // g(253)
      F4 gm1 = (r4v - r2v) * i2hx;                       // g(254)
      F4 gN = (3.0f * r4v - 4.0f * r3v + r2v) * i2hx;    // g(255) edge
      pdx4 = gN;
      t14 = (3.0f * (kCv * gN) - 4.0f * (kBv * gm1) + kAv * gm2) * i2hx;
      pdxx4 = (3.0f * gN - 4.0f * gm1 + gm2) * i2hx;
      kdx4 = (3.0f * kCv - 4.0f * kBv + kAv) * i2hx;
      kcen = kCv; pcen = r4v;
    }

    // ---- neighbor columns via cross-lane shuffles ----
    float pm2 = __shfl_up(pcen.z, 1);
    float pm1 = __shfl_up(pcen.w, 1);
    float pp4 = __shfl_down(pcen.x, 1);
    float pp5 = __shfl_down(pcen.y, 1);
    float km1 = __shfl_up(kcen.w, 1);
    float kp4 = __shfl_down(kcen.x, 1);

    float pcy[8] = {pm2, pm1, pcen.x, pcen.y, pcen.z, pcen.w, pp4, pp5};
    float kcy[6] = {km1, kcen.x, kcen.y, kcen.z, kcen.w, kp4};
    float pdxa[4] = {pdx4.x, pdx4.y, pdx4.z, pdx4.w};
    float t1a[4] = {t14.x, t14.y, t14.z, t14.w};
    float pdxxa[4] = {pdxx4.x, pdxx4.y, pdxx4.z, pdxx4.w};
    float kdxa[4] = {kdx4.x, kdx4.y, kdx4.z, kdx4.w};

    float divka[4];
    unsigned mcur = 0;
#pragma unroll
    for (int q = 0; q < 4; ++q) {
      float pdy, t2, pdyy, kdy;
      const bool edgeL = (j0 == 0) && (q <= 1);
      const bool edgeR = (j0 == WW - 4) && (q >= 2);
      if (!edgeL && !edgeR) {
        float gm = (pcy[2 + q] - pcy[0 + q]) * i2hy;
        float gp = (pcy[4 + q] - pcy[2 + q]) * i2hy;
        pdy = (pcy[3 + q] - pcy[1 + q]) * i2hy;
        t2 = (kcy[2 + q] * gp - kcy[q] * gm) * i2hy;
        pdyy = (gp - gm) * i2hy;
        kdy = (kcy[2 + q] - kcy[q]) * i2hy;
      } else if (edgeL && q == 0) {  // j==0
        float g0 = (4.0f * pcy[3] - 3.0f * pcy[2] - pcy[4]) * i2hy;
        float g1 = (pcy[4] - pcy[2]) * i2hy;
        float g2 = (pcy[5] - pcy[3]) * i2hy;
        pdy = g0;
        t2 = (4.0f * (kcy[2] * g1) - 3.0f * (kcy[1] * g0) - kcy[3] * g2) * i2hy;
        pdyy = (4.0f * g1 - 3.0f * g0 - g2) * i2hy;
        kdy = (4.0f * kcy[2] - 3.0f * kcy[1] - kcy[3]) * i2hy;
      } else if (edgeL) {  // j==1
        float gm = (4.0f * pcy[3] - 3.0f * pcy[2] - pcy[4]) * i2hy;  // gy(0)
        float gp = (pcy[5] - pcy[3]) * i2hy;                          // gy(2)
        pdy = (pcy[4] - pcy[2]) * i2hy;
        t2 = (kcy[3] * gp - kcy[1] * gm) * i2hy;
        pdyy = (gp - gm) * i2hy;
        kdy = (kcy[3] - kcy[1]) * i2hy;
      } else if (q == 2) {  // j==254
        float gm = (pcy[4] - pcy[2]) * i2hy;                          // gy(253)
        float gp = (3.0f * pcy[5] - 4.0f * pcy[4] + pcy[3]) * i2hy;   // gy(255)
        pdy = (pcy[5] - pcy[3]) * i2hy;
        t2 = (kcy[4] * gp - kcy[2] * gm) * i2hy;
        pdyy = (gp - gm) * i2hy;
        kdy = (kcy[4] - kcy[2]) * i2hy;
      } else {  // j==255
        float gm2 = (pcy[4] - pcy[2]) * i2hy;
        float gm1 = (pcy[5] - pcy[3]) * i2hy;
        float gN = (3.0f * pcy[5] - 4.0f * pcy[4] + pcy[3]) * i2hy;
        pdy = gN;
        t2 = (3.0f * (kcy[4] * gN) - 4.0f * (kcy[3] * gm1) + kcy[2] * gm2) * i2hy;
        pdyy = (3.0f * gN - 4.0f * gm1 + gm2) * i2hy;
        kdy = (3.0f * kcy[4] - 4.0f * kcy[3] + kcy[2]) * i2hy;
      }

      divka[q] = t1a[q] + t2;
      float divk2 = (pdxxa[q] + pdyy) * kcy[1 + q] + pdxa[q] * kdxa[q] + pdy * kdy;
      mcur |= (fabsf(divka[q] - divk2) < 100.0f) ? (1u << q) : 0u;
    }

    // ---- deferred time-gradient completion + state roll ----
    const bool doCompl = (s >= ((c == 0) ? 2 : 1));
    const bool special0 = (c == 0) && (s == 2);
    const bool edgeN = (c == NCH - 1) && (s == CHUNK - 1);  // t == 31
    float cTa[4] = {pcen.x, pcen.y, pcen.z, pcen.w};
    float pn = 0.0f;
    int pd = 0;
#pragma unroll
    for (int q = 0; q < 4; ++q) {
      const float cT = cTa[q];
      if (doCompl) {
        float pdt = (cT - cm2[q]) * 0.5f;
        float d = dkB[q] - pdt * Sc;
        if (mBb & (1u << q)) { pn += d * d; pd += 1; }
        if (special0) {
          float pdt0 = (4.0f * cm1[q] - 3.0f * cm2[q] - cT) * 0.5f;
          float d0 = dkA[q] - pdt0 * Sc;
          if (mAb & (1u << q)) { pn += d0 * d0; pd += 1; }
        }
      }
      if (edgeN) {
        float pdtN = (3.0f * cT - 4.0f * cm1[q] + cm2[q]) * 0.5f;
        float dN = divka[q] - pdtN * Sc;
        if (mcur & (1u << q)) { pn += dN * dN; pd += 1; }
      }
      dkA[q] = dkB[q]; dkB[q] = divka[q];
      cm2[q] = cm1[q]; cm1[q] = cT;
    }
    mAb = mBb; mBb = mcur;
    accN += (double)pn;
    accD += pd;
  }
#undef ISSUE8

  // ---- post-halo: complete plane t0+CHUNK-1 with c(t0+CHUNK) ----
  if (hasPost) {
    float cPa[4] = {chPost.x, chPost.y, chPost.z, chPost.w};
    float pn = 0.0f;
    int pd = 0;
#pragma unroll
    for (int q = 0; q < 4; ++q) {
      float pdt = (cPa[q] - cm2[q]) * 0.5f;
      float d = dkB[q] - pdt * Sc;
      if (mBb & (1u << q)) { pn += d * d; pd += 1; }
    }
    accN += (double)pn;
    accD += pd;
  }

  // ---- wave + block reduction ----
  for (int off = 32; off > 0; off >>= 1) {
    accN += __shfl_down(accN, off);
    accD += __shfl_down(accD, off);
  }
  if (lane == 0) { redN[wid] = accN; redD[wid] = accD; }
  __syncthreads();
  if (tid == 0) {
    double n = 0.0; long long dd = 0;
    for (int w = 0; w < 4; ++w) { n += redN[w]; dd += redD[w]; }
    const int slot = (((b << 6) + rg) << 2) + c;   // b*256 + rg*4 + c, 0..4095
    ws[slot] = n;
    ws[4096 + slot] = (double)dd;
  }
}

__global__ void pil_final(const double* __restrict__ ws, float* __restrict__ out) {
  __shared__ double s[16];
  const int tid = threadIdx.x;   // 256 threads
  const int b = tid >> 4;        // batch 0..15
  const int k = tid & 15;        // 16 threads per batch, 16 slots each
  double n = 0.0, d = 0.0;
  const int base = (b << 8) + (k << 4);
#pragma unroll
  for (int sidx = 0; sidx < 16; ++sidx) {
    n += ws[base + sidx];
    d += ws[4096 + base + sidx];
  }
  for (int off = 8; off > 0; off >>= 1) {
    n += __shfl_down(n, off, 16);
    d += __shfl_down(d, off, 16);
  }
  if (k == 0) s[b] = n / d;
  __syncthreads();
  if (tid == 0) {
    double acc = 0.0;
    for (int bb = 0; bb < 16; ++bb) acc += s[bb];
    out[0] = (float)(acc / 16.0);
  }
}

extern "C" void kernel_launch(void* const* d_in, const int* in_sizes, int n_in,
                              void* d_out, int out_size, void* d_ws, size_t ws_size,
                              hipStream_t stream) {
  const float* p = (const float*)d_in[0];
  const float* K = (const float*)d_in[1];
  double* ws = (double*)d_ws;
  float* out = (float*)d_out;
  dim3 grid(HH / 4, 16, NCH);  // (64 row-groups, 16 batches, 4 T-chunks) = 4096 blocks
  pil_main<<<grid, 256, 0, stream>>>(p, K, ws);
  pil_final<<<1, 256, 0, stream>>>(ws, out);
}